// Round 7
// baseline (1035.557 us; speedup 1.0000x reference)
//
#include <hip/hip_runtime.h>
#include <stdint.h>

#define D_DIM 1024
#define M_TOT 16384        // rows per stream (8*2048)
#define M2 32768           // fused enc+tgt rows
#define N_LAYERS 3
#define NT 32              // K steps (K=1024 / BK=32)

typedef unsigned short u16;
typedef __attribute__((ext_vector_type(8))) short bf16x8;
typedef __attribute__((ext_vector_type(4))) float f32x4;
typedef __attribute__((ext_vector_type(4))) unsigned short u16x4;

typedef __attribute__((address_space(1))) void gvoid_t;
typedef __attribute__((address_space(3))) void lvoid_t;

__device__ __forceinline__ float b2f(u16 u) {
  union { unsigned int i; float f; } x; x.i = ((unsigned int)u) << 16; return x.f;
}
__device__ __forceinline__ u16 f2b(float f) {  // RNE f32 -> bf16
  union { float f; unsigned int i; } x; x.f = f;
  unsigned int r = x.i + 0x7fffu + ((x.i >> 16) & 1u);
  return (u16)(r >> 16);
}

__device__ __forceinline__ void gload_lds16(const void* g, void* l) {
  __builtin_amdgcn_global_load_lds((gvoid_t*)(uintptr_t)g,
                                   (lvoid_t*)(unsigned int)(uintptr_t)l, 16, 0, 0);
}

// ---------------------------------------------------------------------------
// m97-style 128x128 GEMM engine: BK=32, 4 waves (2x2), 32KB LDS dbuf,
// 2-barrier K-loop, plain C++ LDS reads, ~3 blocks/CU for cross-block overlap.
// B row-major [N x K] (B^T GEMM). Per-wg weight-set select (fused stacks):
// bmTile < split -> (B_a, bias_a, dec_a) else (B_b, bias_b, dec_b).
// EPI 0: outB = bf16(sigmoid(acc+bias) * xfB * decay)
// EPI 1: outB = bf16(acc + bias + xfB)           (pre-LN)
// EPI 2: outB = bf16(p*(acc+bias))               (MoE e0)
// EPI 3: outB = bf16(outB + p*(acc+bias))        (MoE e1,e2)
// EPI 4: outF = outB + p*(acc+bias)              (MoE e3, final f32)
// ---------------------------------------------------------------------------
template <int EPI>
__global__ __launch_bounds__(256) void gemm97(
    const u16* __restrict__ A,
    const u16* __restrict__ B_a, const u16* __restrict__ B_b,
    const float* __restrict__ bias_a, const float* __restrict__ bias_b,
    const float* __restrict__ dec_a, const float* __restrict__ dec_b,
    const u16* __restrict__ xfB, const float* __restrict__ probs, int eIdx,
    int mTiles, int split,
    u16* __restrict__ outB, float* __restrict__ outF)
{
  __shared__ __align__(128) u16 lds[16384];   // 32KB: 2 buf x {A 8KB, B 8KB}
  const char* ldsc = (const char*)lds;
  int t = threadIdx.x;
  int wid = t >> 6, l = t & 63;
  int wm = wid >> 1, wn = wid & 1;            // 2x2 waves; wave tile 64x64
  int lm = l & 15, g = l >> 4;

  int nwg = mTiles * 8;
  int orig = blockIdx.x;
  int wg = (orig & 7) * (nwg >> 3) + (orig >> 3);   // bijective (nwg%8==0)
  int bmT = wg >> 3, bnT = wg & 7;
  int bm0 = bmT << 7, bn0 = bnT << 7;

  const u16*  Bm   = (bmT < split) ? B_a   : B_b;
  const float* bias = (bmT < split) ? bias_a : bias_b;
  const float* dec  = (bmT < split) ? dec_a  : dec_b;

  // staging: 4 threads per 64B row (16B each), 64 rows per round, 2 rounds/matrix.
  // pre-swizzled source quarter: physical slot q holds logical quarter q^(row&3).
  int rowS = t >> 2, q = t & 3;
  int colE = ((q ^ (rowS & 3)) << 3);         // element offset within 32-elem row
  const u16* pA = A  + (size_t)(bm0 + rowS) * D_DIM + colE;
  const u16* pB = Bm + (size_t)(bn0 + rowS) * D_DIM + colE;
  u16* dW = lds + wid * 512;                  // wave-uniform dst (+lane*16B implicit)

  auto stage = [&](int kt, int buf) {
    const u16* a0 = pA + kt * 32;
    const u16* b0 = pB + kt * 32;
    u16* d = dW + buf * 8192;
    gload_lds16(a0,             d);           // A rows 0-63
    gload_lds16(a0 + 64 * D_DIM, d + 2048);   // A rows 64-127
    gload_lds16(b0,             d + 4096);    // B rows 0-63
    gload_lds16(b0 + 64 * D_DIM, d + 6144);   // B rows 64-127
  };

  f32x4 acc[4][4];
#pragma unroll
  for (int mi = 0; mi < 4; mi++)
#pragma unroll
    for (int ni = 0; ni < 4; ni++) acc[mi][ni] = 0.0f;

  stage(0, 0);
  int buf = 0;
  for (int kt = 0; kt < NT; ++kt) {
    if (kt + 1 < NT) stage(kt + 1, buf ^ 1);
    __syncthreads();                           // stage(kt) landed (vmcnt0 by compiler)
    {
      const char* base = ldsc + buf * 16384;
      // logical quarter g lives at physical g^(row&3); row&3 == lm&3 here.
      unsigned sw = ((unsigned)(g * 16)) ^ ((unsigned)(lm & 3) << 4);
      bf16x8 av[4], bv[4];
#pragma unroll
      for (int mi = 0; mi < 4; mi++) {
        unsigned row = wm * 64 + mi * 16 + lm;
        av[mi] = *(const bf16x8*)(base + row * 64 + sw);
      }
#pragma unroll
      for (int ni = 0; ni < 4; ni++) {
        unsigned row = wn * 64 + ni * 16 + lm;
        bv[ni] = *(const bf16x8*)(base + 8192 + row * 64 + sw);
      }
#pragma unroll
      for (int mi = 0; mi < 4; mi++)
#pragma unroll
        for (int ni = 0; ni < 4; ni++)
          acc[mi][ni] = __builtin_amdgcn_mfma_f32_16x16x32_bf16(av[mi], bv[ni], acc[mi][ni], 0, 0, 0);
    }
    __syncthreads();                           // reads done before next stage overwrites
    buf ^= 1;
  }

  // ---- epilogue ----  m = bm0+wm*64+mi*16+(l>>4)*4+j, n = bn0+wn*64+ni*16+lm
  int nidx[4]; float bia[4], dcv[4];
#pragma unroll
  for (int ni = 0; ni < 4; ni++) {
    nidx[ni] = bn0 + wn * 64 + ni * 16 + lm;
    bia[ni] = bias[nidx[ni]];
    dcv[ni] = (EPI == 0) ? dec[nidx[ni]] : 0.0f;
  }
#pragma unroll
  for (int mi = 0; mi < 4; mi++)
#pragma unroll
    for (int j = 0; j < 4; j++) {
      size_t m = (size_t)bm0 + wm * 64 + mi * 16 + g * 4 + j;
      if (EPI == 0) {
        const u16* xr = xfB + m * D_DIM;
        u16* orow = outB + m * D_DIM;
#pragma unroll
        for (int ni = 0; ni < 4; ni++) {
          float v = acc[mi][ni][j] + bia[ni];
          float gt = 1.0f / (1.0f + __expf(-v));
          orow[nidx[ni]] = f2b(gt * b2f(xr[nidx[ni]]) * dcv[ni]);
        }
      } else if (EPI == 1) {
        const u16* xr = xfB + m * D_DIM;
        u16* orow = outB + m * D_DIM;
#pragma unroll
        for (int ni = 0; ni < 4; ni++)
          orow[nidx[ni]] = f2b(acc[mi][ni][j] + bia[ni] + b2f(xr[nidx[ni]]));
      } else if (EPI == 2) {
        float p = probs[m * 4 + eIdx];
        u16* orow = outB + m * D_DIM;
#pragma unroll
        for (int ni = 0; ni < 4; ni++)
          orow[nidx[ni]] = f2b(p * (acc[mi][ni][j] + bia[ni]));
      } else if (EPI == 3) {
        float p = probs[m * 4 + eIdx];
        u16* orow = outB + m * D_DIM;
#pragma unroll
        for (int ni = 0; ni < 4; ni++)
          orow[nidx[ni]] = f2b(b2f(orow[nidx[ni]]) + p * (acc[mi][ni][j] + bia[ni]));
      } else {
        float p = probs[m * 4 + eIdx];
        const u16* srow = outB + m * D_DIM;
        float* orow = outF + m * D_DIM;
#pragma unroll
        for (int ni = 0; ni < 4; ni++)
          orow[nidx[ni]] = b2f(srow[nidx[ni]]) + p * (acc[mi][ni][j] + bia[ni]);
      }
    }
}

// Fused-stack LayerNorm over D=1024 (rows<M_TOT -> tgt params, else enc).
// Writes bf16 next-A; optionally f32 (tgt rows only, final tgt layer).
__global__ __launch_bounds__(256) void ln_fused(const u16* __restrict__ src,
                                                const float* __restrict__ gamT,
                                                const float* __restrict__ betT,
                                                const float* __restrict__ gamE,
                                                const float* __restrict__ betE,
                                                float* __restrict__ dstF,
                                                u16* __restrict__ dstB) {
  size_t row = blockIdx.x;
  const float* gamma = (row < M_TOT) ? gamT : gamE;
  const float* beta  = (row < M_TOT) ? betT : betE;
  int t = threadIdx.x, w = t >> 6, l = t & 63;
  u16x4 vb = ((const u16x4*)(src + row * D_DIM))[t];
  float v[4];
#pragma unroll
  for (int i = 0; i < 4; i++) v[i] = b2f(vb[i]);
  float s = v[0] + v[1] + v[2] + v[3];
  float qs = v[0]*v[0] + v[1]*v[1] + v[2]*v[2] + v[3]*v[3];
#pragma unroll
  for (int off = 32; off; off >>= 1) { s += __shfl_xor(s, off); qs += __shfl_xor(qs, off); }
  __shared__ float red[8];
  if (l == 0) { red[w] = s; red[4 + w] = qs; }
  __syncthreads();
  s = red[0] + red[1] + red[2] + red[3];
  qs = red[4] + red[5] + red[6] + red[7];
  float mu = s * (1.0f / 1024.0f);
  float var = qs * (1.0f / 1024.0f) - mu * mu;
  float inv = rsqrtf(var + 1e-5f);
  f32x4 gm = ((const f32x4*)gamma)[t], b = ((const f32x4*)beta)[t];
  f32x4 y; u16x4 yb;
#pragma unroll
  for (int i = 0; i < 4; i++) { y[i] = (v[i] - mu) * inv * gm[i] + b[i]; yb[i] = f2b(y[i]); }
  ((u16x4*)(dstB + row * D_DIM))[t] = yb;
  if (dstF != nullptr && row < M_TOT) ((f32x4*)(dstF + row * D_DIM))[t] = y;
}

// f32 -> bf16 elementwise
__global__ void conv_kernel(const float* __restrict__ src, u16* __restrict__ dst, int n4) {
  int i = blockIdx.x * 256 + threadIdx.x;
  if (i >= n4) return;
  f32x4 v = ((const f32x4*)src)[i];
  u16x4 o;
#pragma unroll
  for (int j = 0; j < 4; j++) o[j] = f2b(v[j]);
  ((u16x4*)dst)[i] = o;
}

// Gate: logits + softmax -> probs[m,0..3]. One wave per row.
__global__ __launch_bounds__(256) void gate_kernel(const u16* __restrict__ zb,
                                                   const float* __restrict__ gW,
                                                   const float* __restrict__ gb,
                                                   float* __restrict__ probs) {
  __shared__ float sW[4096];
  int t = threadIdx.x;
#pragma unroll
  for (int c = 0; c < 4; c++) ((f32x4*)sW)[c * 256 + t] = ((const f32x4*)gW)[c * 256 + t];
  __syncthreads();
  int w = t >> 6, l = t & 63;
  size_t m = (size_t)blockIdx.x * 4 + w;
  const u16* zr = zb + m * D_DIM;
  float d0 = 0, d1 = 0, d2 = 0, d3 = 0;
#pragma unroll
  for (int c = 0; c < 4; c++) {
    int k = l * 4 + c * 256;
    u16x4 zv = *(const u16x4*)(zr + k);
    f32x4 w0 = *(const f32x4*)&sW[k];
    f32x4 w1 = *(const f32x4*)&sW[1024 + k];
    f32x4 w2 = *(const f32x4*)&sW[2048 + k];
    f32x4 w3 = *(const f32x4*)&sW[3072 + k];
#pragma unroll
    for (int i = 0; i < 4; i++) {
      float zf = b2f(zv[i]);
      d0 += zf * w0[i]; d1 += zf * w1[i]; d2 += zf * w2[i]; d3 += zf * w3[i];
    }
  }
#pragma unroll
  for (int off = 32; off; off >>= 1) {
    d0 += __shfl_xor(d0, off); d1 += __shfl_xor(d1, off);
    d2 += __shfl_xor(d2, off); d3 += __shfl_xor(d3, off);
  }
  if (l == 0) {
    float l0 = d0 + gb[0], l1 = d1 + gb[1], l2 = d2 + gb[2], l3 = d3 + gb[3];
    float mx = fmaxf(fmaxf(l0, l1), fmaxf(l2, l3));
    float e0 = __expf(l0 - mx), e1 = __expf(l1 - mx), e2 = __expf(l2 - mx), e3 = __expf(l3 - mx);
    float inv = 1.0f / (e0 + e1 + e2 + e3);
    f32x4 r; r[0] = e0 * inv; r[1] = e1 * inv; r[2] = e2 * inv; r[3] = e3 * inv;
    ((f32x4*)(probs + m * 4))[0] = r;
  }
}

extern "C" void kernel_launch(void* const* d_in, const int* in_sizes, int n_in,
                              void* d_out, int out_size, void* d_ws, size_t ws_size,
                              hipStream_t stream) {
  (void)in_sizes; (void)n_in; (void)out_size; (void)ws_size;
  const float* x_ctx    = (const float*)d_in[0];
  const float* x_tgt    = (const float*)d_in[1];
  const float* enc_Win  = (const float*)d_in[2];
  const float* enc_bin  = (const float*)d_in[3];
  const float* enc_dec  = (const float*)d_in[4];
  const float* enc_Wout = (const float*)d_in[5];
  const float* enc_bout = (const float*)d_in[6];
  const float* enc_gam  = (const float*)d_in[7];
  const float* enc_bet  = (const float*)d_in[8];
  const float* tgt_Win  = (const float*)d_in[9];
  const float* tgt_bin  = (const float*)d_in[10];
  const float* tgt_dec  = (const float*)d_in[11];
  const float* tgt_Wout = (const float*)d_in[12];
  const float* tgt_bout = (const float*)d_in[13];
  const float* tgt_gam  = (const float*)d_in[14];
  const float* tgt_bet  = (const float*)d_in[15];
  const float* gate_W   = (const float*)d_in[16];
  const float* gate_b   = (const float*)d_in[17];
  const float* exp_W    = (const float*)d_in[18];
  const float* exp_b    = (const float*)d_in[19];

  // d_out: pred_z[16M f32] | gate_probs[64K] | z_target[16M f32]
  float* out_pred  = (float*)d_out;
  float* out_probs = out_pred + (size_t)M_TOT * D_DIM;
  float* out_ztgt  = out_probs + (size_t)M_TOT * 4;

  // ws: bf16 weights (32MB) | xb2 (64MB) | sb2 (64MB) = 160MB.
  // ob2 (pre-LN, 64MB bf16) lives in the out_pred slot (free until final MoE pass).
  char* ws = (char*)d_ws;
  u16* wbTgtIn  = (u16*)ws;
  u16* wbTgtOut = wbTgtIn  + (size_t)3 * 1048576;
  u16* wbEncIn  = wbTgtOut + (size_t)3 * 1048576;
  u16* wbEncOut = wbEncIn  + (size_t)3 * 1048576;
  u16* wbExp    = wbEncOut + (size_t)3 * 1048576;
  u16* xb2      = wbExp    + (size_t)4 * 1048576;
  u16* sb2      = xb2 + (size_t)M2 * D_DIM;
  u16* ob2      = (u16*)out_pred;
  u16* xbCtx    = xb2 + (size_t)M_TOT * D_DIM;

  auto conv = [&](const float* s, u16* d, size_t n) {
    int n4 = (int)(n / 4);
    conv_kernel<<<(n4 + 255) / 256, 256, 0, stream>>>(s, d, n4);
  };
  conv(tgt_Win,  wbTgtIn,  (size_t)3 * 1048576);
  conv(tgt_Wout, wbTgtOut, (size_t)3 * 1048576);
  conv(enc_Win,  wbEncIn,  (size_t)3 * 1048576);
  conv(enc_Wout, wbEncOut, (size_t)3 * 1048576);
  conv(exp_W,    wbExp,    (size_t)4 * 1048576);
  conv(x_tgt, xb2,   (size_t)M_TOT * D_DIM);
  conv(x_ctx, xbCtx, (size_t)M_TOT * D_DIM);

  // ---- fused liquid stacks (rows 0..16383 = tgt, 16384..32767 = enc/ctx) ----
  for (int i = 0; i < N_LAYERS; i++) {
    size_t wo = (size_t)i * 1048576;
    gemm97<0><<<M2 / 128 * 8, 256, 0, stream>>>(
        xb2, wbTgtIn + wo, wbEncIn + wo,
        tgt_bin + i * 1024, enc_bin + i * 1024,
        tgt_dec + i * 1024, enc_dec + i * 1024,
        xb2, nullptr, 0, M2 / 128, M_TOT / 128, sb2, nullptr);
    gemm97<1><<<M2 / 128 * 8, 256, 0, stream>>>(
        sb2, wbTgtOut + wo, wbEncOut + wo,
        tgt_bout + i * 1024, enc_bout + i * 1024,
        nullptr, nullptr,
        xb2, nullptr, 0, M2 / 128, M_TOT / 128, ob2, nullptr);
    ln_fused<<<M2, 256, 0, stream>>>(ob2,
        tgt_gam + i * 1024, tgt_bet + i * 1024,
        enc_gam + i * 1024, enc_bet + i * 1024,
        (i == N_LAYERS - 1) ? out_ztgt : nullptr, xb2);
  }

  // ---- MoE head on ctx half: gate, then 4 passes (bf16 running sum in sb2) ----
  gate_kernel<<<M_TOT / 4, 256, 0, stream>>>(xbCtx, gate_W, gate_b, out_probs);
  int moeWgs = M_TOT / 128 * 8;
  gemm97<2><<<moeWgs, 256, 0, stream>>>(xbCtx, wbExp,               nullptr,
      exp_b,        nullptr, nullptr, nullptr, nullptr, out_probs, 0,
      M_TOT / 128, 1 << 30, sb2, nullptr);
  gemm97<3><<<moeWgs, 256, 0, stream>>>(xbCtx, wbExp + 1048576,     nullptr,
      exp_b + 1024, nullptr, nullptr, nullptr, nullptr, out_probs, 1,
      M_TOT / 128, 1 << 30, sb2, nullptr);
  gemm97<3><<<moeWgs, 256, 0, stream>>>(xbCtx, wbExp + 2 * 1048576, nullptr,
      exp_b + 2048, nullptr, nullptr, nullptr, nullptr, out_probs, 2,
      M_TOT / 128, 1 << 30, sb2, nullptr);
  gemm97<4><<<moeWgs, 256, 0, stream>>>(xbCtx, wbExp + 3 * 1048576, nullptr,
      exp_b + 3072, nullptr, nullptr, nullptr, nullptr, out_probs, 3,
      M_TOT / 128, 1 << 30, sb2, out_pred);
}

// Round 8
// 1000.864 us; speedup vs baseline: 1.0347x; 1.0347x over previous
//
#include <hip/hip_runtime.h>
#include <stdint.h>

#define D_DIM 1024
#define M_TOT 16384        // rows per stream (8*2048)
#define M2 32768           // fused enc+tgt rows
#define N_LAYERS 3
#define NT 16              // K tiles (K=1024 / BK=64)

typedef unsigned short u16;
typedef __attribute__((ext_vector_type(8))) short bf16x8;
typedef __attribute__((ext_vector_type(16))) float f32x16;
typedef __attribute__((ext_vector_type(4))) float f32x4;
typedef __attribute__((ext_vector_type(4))) unsigned short u16x4;

typedef __attribute__((address_space(1))) void gvoid_t;
typedef __attribute__((address_space(3))) void lvoid_t;

__device__ __forceinline__ float b2f(u16 u) {
  union { unsigned int i; float f; } x; x.i = ((unsigned int)u) << 16; return x.f;
}
__device__ __forceinline__ u16 f2b(float f) {  // RNE f32 -> bf16
  union { float f; unsigned int i; } x; x.f = f;
  unsigned int r = x.i + 0x7fffu + ((x.i >> 16) & 1u);
  return (u16)(r >> 16);
}

__device__ __forceinline__ void gload_lds16(const void* g, void* l) {
  __builtin_amdgcn_global_load_lds((gvoid_t*)(uintptr_t)g,
                                   (lvoid_t*)(unsigned int)(uintptr_t)l, 16, 0, 0);
}

// ---------------------------------------------------------------------------
// m97-geometry GEMM engine, 32x32x16 MFMA fragments.
// 128x128 tile, BK=64, 256 thr (2x2 waves, wave tile 64x64, 2x2 frags 32x32),
// 64KB LDS double-buffer -> 2 blocks/CU (cross-block DS||MFMA overlap, m114),
// plain 2-barrier K-loop, plain C++ LDS reads (compiler counted lgkmcnt).
// LDS rows 128B; staged with chunk ^= (row&7) pre-swizzle; reads XOR the same
// -> conflict-free (32 lanes/frag cover 32 banks exactly once).
// B row-major [N x K] (B^T GEMM). Fused stacks: bmTile<split -> set a, else b.
// EPI 0: outB = bf16(sigmoid(acc+bias) * xfB * decay)
// EPI 1: outB = bf16(acc + bias + xfB)           (pre-LN)
// EPI 2: outB = bf16(p*(acc+bias))               (MoE e0)
// EPI 3: outB = bf16(outB + p*(acc+bias))        (MoE e1,e2)
// EPI 4: outF = outB + p*(acc+bias)              (MoE e3, final f32)
// ---------------------------------------------------------------------------
template <int EPI>
__global__ __launch_bounds__(256, 2) void gemm97(
    const u16* __restrict__ A,
    const u16* __restrict__ B_a, const u16* __restrict__ B_b,
    const float* __restrict__ bias_a, const float* __restrict__ bias_b,
    const float* __restrict__ dec_a, const float* __restrict__ dec_b,
    const u16* __restrict__ xfB, const float* __restrict__ probs, int eIdx,
    int mTiles, int split,
    u16* __restrict__ outB, float* __restrict__ outF)
{
  __shared__ __align__(128) u16 lds[32768];   // 64KB: 2 buf x {A 16KB, B 16KB}
  const char* ldsc = (const char*)lds;
  int t = threadIdx.x;
  int wid = t >> 6, l = t & 63;
  int wm = wid >> 1, wn = wid & 1;            // 2x2 waves; wave tile 64x64
  int l31 = l & 31, hi = l >> 5;

  int nwg = mTiles * 8;
  int orig = blockIdx.x;
  int wg = (orig & 7) * (nwg >> 3) + (orig >> 3);   // bijective (nwg % 8 == 0)
  int bmT = wg >> 3, bnT = wg & 7;
  int bm0 = bmT << 7, bn0 = bnT << 7;

  const u16*  Bm   = (bmT < split) ? B_a   : B_b;
  const float* bias = (bmT < split) ? bias_a : bias_b;
  const float* dec  = (bmT < split) ? dec_a  : dec_b;

  // staging: 8 threads per 128B row (16B each), 32 rows/round, 4 rounds/matrix.
  // pre-swizzle: physical chunk c holds logical chunk c ^ (row&7).
  int rowS = t >> 3;                          // 0..31
  int colE = ((t & 7) ^ (rowS & 7)) << 3;     // element col within 64-elem row
  const u16* pA = A  + (size_t)(bm0 + rowS) * D_DIM + colE;
  const u16* pB = Bm + (size_t)(bn0 + rowS) * D_DIM + colE;
  u16* dW = lds + wid * 512;                  // wave-uniform dst (lane*16B implicit)

  auto stage = [&](int kt, int bf) {
    const u16* a0 = pA + kt * 64;
    const u16* b0 = pB + kt * 64;
    u16* d = dW + bf * 16384;
#pragma unroll
    for (int r = 0; r < 4; r++) {
      gload_lds16(a0 + (size_t)r * 32 * D_DIM, d + r * 2048);
      gload_lds16(b0 + (size_t)r * 32 * D_DIM, d + 8192 + r * 2048);
    }
  };

  f32x16 acc[2][2];
#pragma unroll
  for (int fm = 0; fm < 2; fm++)
#pragma unroll
    for (int fn = 0; fn < 2; fn++) acc[fm][fn] = 0.0f;

  // read-side addresses: row base (A: m-row, B: n-row), swizzled k-cols
  unsigned rbA = (unsigned)((wm * 64 + l31) * 128);
  unsigned rbB = (unsigned)(16384 + (wn * 64 + l31) * 128);
  unsigned kc[4];
#pragma unroll
  for (int ks = 0; ks < 4; ks++)
    kc[ks] = (unsigned)((ks * 32 + hi * 16) ^ ((l & 7) << 4));

  stage(0, 0);
  int buf = 0;
  for (int kt = 0; kt < NT; ++kt) {
    if (kt + 1 < NT) stage(kt + 1, buf ^ 1);
    __syncthreads();                           // stage(kt) landed
    {
      const char* base = ldsc + buf * 32768;
      bf16x8 av[2][4], bv[2][4];
#pragma unroll
      for (int fm = 0; fm < 2; fm++)
#pragma unroll
        for (int ks = 0; ks < 4; ks++)
          av[fm][ks] = *(const bf16x8*)(base + rbA + fm * 4096 + kc[ks]);
#pragma unroll
      for (int fn = 0; fn < 2; fn++)
#pragma unroll
        for (int ks = 0; ks < 4; ks++)
          bv[fn][ks] = *(const bf16x8*)(base + rbB + fn * 4096 + kc[ks]);
#pragma unroll
      for (int ks = 0; ks < 4; ks++)
#pragma unroll
        for (int fm = 0; fm < 2; fm++)
#pragma unroll
          for (int fn = 0; fn < 2; fn++)
            acc[fm][fn] = __builtin_amdgcn_mfma_f32_32x32x16_bf16(
                av[fm][ks], bv[fn][ks], acc[fm][fn], 0, 0, 0);
    }
    __syncthreads();                           // reads done before overwrite
    buf ^= 1;
  }

  // ---- epilogue ---- 32x32 C/D layout: col = l&31, row = (r&3)+8*(r>>2)+4*hi
  int nidx[2]; float bia[2], dcv[2];
#pragma unroll
  for (int fn = 0; fn < 2; fn++) {
    nidx[fn] = bn0 + wn * 64 + fn * 32 + l31;
    bia[fn] = bias[nidx[fn]];
    dcv[fn] = (EPI == 0) ? dec[nidx[fn]] : 0.0f;
  }
#pragma unroll
  for (int fm = 0; fm < 2; fm++)
#pragma unroll
    for (int r = 0; r < 16; r++) {
      size_t m = (size_t)bm0 + wm * 64 + fm * 32 + (r & 3) + ((r >> 2) << 3) + (hi << 2);
      if (EPI == 0) {
        const u16* xr = xfB + m * D_DIM;
        u16* orow = outB + m * D_DIM;
#pragma unroll
        for (int fn = 0; fn < 2; fn++) {
          float v = acc[fm][fn][r] + bia[fn];
          float gt = 1.0f / (1.0f + __expf(-v));
          orow[nidx[fn]] = f2b(gt * b2f(xr[nidx[fn]]) * dcv[fn]);
        }
      } else if (EPI == 1) {
        const u16* xr = xfB + m * D_DIM;
        u16* orow = outB + m * D_DIM;
#pragma unroll
        for (int fn = 0; fn < 2; fn++)
          orow[nidx[fn]] = f2b(acc[fm][fn][r] + bia[fn] + b2f(xr[nidx[fn]]));
      } else if (EPI == 2) {
        float p = probs[m * 4 + eIdx];
        u16* orow = outB + m * D_DIM;
#pragma unroll
        for (int fn = 0; fn < 2; fn++)
          orow[nidx[fn]] = f2b(p * (acc[fm][fn][r] + bia[fn]));
      } else if (EPI == 3) {
        float p = probs[m * 4 + eIdx];
        u16* orow = outB + m * D_DIM;
#pragma unroll
        for (int fn = 0; fn < 2; fn++)
          orow[nidx[fn]] = f2b(b2f(orow[nidx[fn]]) + p * (acc[fm][fn][r] + bia[fn]));
      } else {
        float p = probs[m * 4 + eIdx];
        const u16* srow = outB + m * D_DIM;
        float* orow = outF + m * D_DIM;
#pragma unroll
        for (int fn = 0; fn < 2; fn++)
          orow[nidx[fn]] = b2f(srow[nidx[fn]]) + p * (acc[fm][fn][r] + bia[fn]);
      }
    }
}

// Fused-stack LayerNorm over D=1024 (rows<M_TOT -> tgt params, else enc).
__global__ __launch_bounds__(256) void ln_fused(const u16* __restrict__ src,
                                                const float* __restrict__ gamT,
                                                const float* __restrict__ betT,
                                                const float* __restrict__ gamE,
                                                const float* __restrict__ betE,
                                                float* __restrict__ dstF,
                                                u16* __restrict__ dstB) {
  size_t row = blockIdx.x;
  const float* gamma = (row < M_TOT) ? gamT : gamE;
  const float* beta  = (row < M_TOT) ? betT : betE;
  int t = threadIdx.x, w = t >> 6, l = t & 63;
  u16x4 vb = ((const u16x4*)(src + row * D_DIM))[t];
  float v[4];
#pragma unroll
  for (int i = 0; i < 4; i++) v[i] = b2f(vb[i]);
  float s = v[0] + v[1] + v[2] + v[3];
  float qs = v[0]*v[0] + v[1]*v[1] + v[2]*v[2] + v[3]*v[3];
#pragma unroll
  for (int off = 32; off; off >>= 1) { s += __shfl_xor(s, off); qs += __shfl_xor(qs, off); }
  __shared__ float red[8];
  if (l == 0) { red[w] = s; red[4 + w] = qs; }
  __syncthreads();
  s = red[0] + red[1] + red[2] + red[3];
  qs = red[4] + red[5] + red[6] + red[7];
  float mu = s * (1.0f / 1024.0f);
  float var = qs * (1.0f / 1024.0f) - mu * mu;
  float inv = rsqrtf(var + 1e-5f);
  f32x4 gm = ((const f32x4*)gamma)[t], b = ((const f32x4*)beta)[t];
  f32x4 y; u16x4 yb;
#pragma unroll
  for (int i = 0; i < 4; i++) { y[i] = (v[i] - mu) * inv * gm[i] + b[i]; yb[i] = f2b(y[i]); }
  ((u16x4*)(dstB + row * D_DIM))[t] = yb;
  if (dstF != nullptr && row < M_TOT) ((f32x4*)(dstF + row * D_DIM))[t] = y;
}

// f32 -> bf16 elementwise
__global__ void conv_kernel(const float* __restrict__ src, u16* __restrict__ dst, int n4) {
  int i = blockIdx.x * 256 + threadIdx.x;
  if (i >= n4) return;
  f32x4 v = ((const f32x4*)src)[i];
  u16x4 o;
#pragma unroll
  for (int j = 0; j < 4; j++) o[j] = f2b(v[j]);
  ((u16x4*)dst)[i] = o;
}

// Gate: logits + softmax -> probs[m,0..3]. One wave per row.
__global__ __launch_bounds__(256) void gate_kernel(const u16* __restrict__ zb,
                                                   const float* __restrict__ gW,
                                                   const float* __restrict__ gb,
                                                   float* __restrict__ probs) {
  __shared__ float sW[4096];
  int t = threadIdx.x;
#pragma unroll
  for (int c = 0; c < 4; c++) ((f32x4*)sW)[c * 256 + t] = ((const f32x4*)gW)[c * 256 + t];
  __syncthreads();
  int w = t >> 6, l = t & 63;
  size_t m = (size_t)blockIdx.x * 4 + w;
  const u16* zr = zb + m * D_DIM;
  float d0 = 0, d1 = 0, d2 = 0, d3 = 0;
#pragma unroll
  for (int c = 0; c < 4; c++) {
    int k = l * 4 + c * 256;
    u16x4 zv = *(const u16x4*)(zr + k);
    f32x4 w0 = *(const f32x4*)&sW[k];
    f32x4 w1 = *(const f32x4*)&sW[1024 + k];
    f32x4 w2 = *(const f32x4*)&sW[2048 + k];
    f32x4 w3 = *(const f32x4*)&sW[3072 + k];
#pragma unroll
    for (int i = 0; i < 4; i++) {
      float zf = b2f(zv[i]);
      d0 += zf * w0[i]; d1 += zf * w1[i]; d2 += zf * w2[i]; d3 += zf * w3[i];
    }
  }
#pragma unroll
  for (int off = 32; off; off >>= 1) {
    d0 += __shfl_xor(d0, off); d1 += __shfl_xor(d1, off);
    d2 += __shfl_xor(d2, off); d3 += __shfl_xor(d3, off);
  }
  if (l == 0) {
    float l0 = d0 + gb[0], l1 = d1 + gb[1], l2 = d2 + gb[2], l3 = d3 + gb[3];
    float mx = fmaxf(fmaxf(l0, l1), fmaxf(l2, l3));
    float e0 = __expf(l0 - mx), e1 = __expf(l1 - mx), e2 = __expf(l2 - mx), e3 = __expf(l3 - mx);
    float inv = 1.0f / (e0 + e1 + e2 + e3);
    f32x4 r; r[0] = e0 * inv; r[1] = e1 * inv; r[2] = e2 * inv; r[3] = e3 * inv;
    ((f32x4*)(probs + m * 4))[0] = r;
  }
}

extern "C" void kernel_launch(void* const* d_in, const int* in_sizes, int n_in,
                              void* d_out, int out_size, void* d_ws, size_t ws_size,
                              hipStream_t stream) {
  (void)in_sizes; (void)n_in; (void)out_size; (void)ws_size;
  const float* x_ctx    = (const float*)d_in[0];
  const float* x_tgt    = (const float*)d_in[1];
  const float* enc_Win  = (const float*)d_in[2];
  const float* enc_bin  = (const float*)d_in[3];
  const float* enc_dec  = (const float*)d_in[4];
  const float* enc_Wout = (const float*)d_in[5];
  const float* enc_bout = (const float*)d_in[6];
  const float* enc_gam  = (const float*)d_in[7];
  const float* enc_bet  = (const float*)d_in[8];
  const float* tgt_Win  = (const float*)d_in[9];
  const float* tgt_bin  = (const float*)d_in[10];
  const float* tgt_dec  = (const float*)d_in[11];
  const float* tgt_Wout = (const float*)d_in[12];
  const float* tgt_bout = (const float*)d_in[13];
  const float* tgt_gam  = (const float*)d_in[14];
  const float* tgt_bet  = (const float*)d_in[15];
  const float* gate_W   = (const float*)d_in[16];
  const float* gate_b   = (const float*)d_in[17];
  const float* exp_W    = (const float*)d_in[18];
  const float* exp_b    = (const float*)d_in[19];

  // d_out: pred_z[16M f32] | gate_probs[64K] | z_target[16M f32]
  float* out_pred  = (float*)d_out;
  float* out_probs = out_pred + (size_t)M_TOT * D_DIM;
  float* out_ztgt  = out_probs + (size_t)M_TOT * 4;

  // ws: bf16 weights (32MB) | xb2 (64MB) | sb2 (64MB) = 160MB.
  // ob2 (pre-LN bf16, 64MB) lives in the out_pred slot (free until final MoE pass).
  char* ws = (char*)d_ws;
  u16* wbTgtIn  = (u16*)ws;
  u16* wbTgtOut = wbTgtIn  + (size_t)3 * 1048576;
  u16* wbEncIn  = wbTgtOut + (size_t)3 * 1048576;
  u16* wbEncOut = wbEncIn  + (size_t)3 * 1048576;
  u16* wbExp    = wbEncOut + (size_t)3 * 1048576;
  u16* xb2      = wbExp    + (size_t)4 * 1048576;
  u16* sb2      = xb2 + (size_t)M2 * D_DIM;
  u16* ob2      = (u16*)out_pred;
  u16* xbCtx    = xb2 + (size_t)M_TOT * D_DIM;

  auto conv = [&](const float* s, u16* d, size_t n) {
    int n4 = (int)(n / 4);
    conv_kernel<<<(n4 + 255) / 256, 256, 0, stream>>>(s, d, n4);
  };
  conv(tgt_Win,  wbTgtIn,  (size_t)3 * 1048576);
  conv(tgt_Wout, wbTgtOut, (size_t)3 * 1048576);
  conv(enc_Win,  wbEncIn,  (size_t)3 * 1048576);
  conv(enc_Wout, wbEncOut, (size_t)3 * 1048576);
  conv(exp_W,    wbExp,    (size_t)4 * 1048576);
  conv(x_tgt, xb2,   (size_t)M_TOT * D_DIM);
  conv(x_ctx, xbCtx, (size_t)M_TOT * D_DIM);

  // ---- fused liquid stacks (rows 0..16383 = tgt, 16384..32767 = enc/ctx) ----
  int nwg2 = M2 / 128 * 8;   // 2048
  for (int i = 0; i < N_LAYERS; i++) {
    size_t wo = (size_t)i * 1048576;
    gemm97<0><<<nwg2, 256, 0, stream>>>(
        xb2, wbTgtIn + wo, wbEncIn + wo,
        tgt_bin + i * 1024, enc_bin + i * 1024,
        tgt_dec + i * 1024, enc_dec + i * 1024,
        xb2, nullptr, 0, M2 / 128, M_TOT / 128, sb2, nullptr);
    gemm97<1><<<nwg2, 256, 0, stream>>>(
        sb2, wbTgtOut + wo, wbEncOut + wo,
        tgt_bout + i * 1024, enc_bout + i * 1024,
        nullptr, nullptr,
        xb2, nullptr, 0, M2 / 128, M_TOT / 128, ob2, nullptr);
    ln_fused<<<M2, 256, 0, stream>>>(ob2,
        tgt_gam + i * 1024, tgt_bet + i * 1024,
        enc_gam + i * 1024, enc_bet + i * 1024,
        (i == N_LAYERS - 1) ? out_ztgt : nullptr, xb2);
  }

  // ---- MoE head on ctx half: gate, then 4 passes (bf16 running sum in sb2) ----
  gate_kernel<<<M_TOT / 4, 256, 0, stream>>>(xbCtx, gate_W, gate_b, out_probs);
  int moeWgs = M_TOT / 128 * 8;   // 1024
  gemm97<2><<<moeWgs, 256, 0, stream>>>(xbCtx, wbExp,               nullptr,
      exp_b,        nullptr, nullptr, nullptr, nullptr, out_probs, 0,
      M_TOT / 128, 1 << 30, sb2, nullptr);
  gemm97<3><<<moeWgs, 256, 0, stream>>>(xbCtx, wbExp + 1048576,     nullptr,
      exp_b + 1024, nullptr, nullptr, nullptr, nullptr, out_probs, 1,
      M_TOT / 128, 1 << 30, sb2, nullptr);
  gemm97<3><<<moeWgs, 256, 0, stream>>>(xbCtx, wbExp + 2 * 1048576, nullptr,
      exp_b + 2048, nullptr, nullptr, nullptr, nullptr, out_probs, 2,
      M_TOT / 128, 1 << 30, sb2, nullptr);
  gemm97<4><<<moeWgs, 256, 0, stream>>>(xbCtx, wbExp + 3 * 1048576, nullptr,
      exp_b + 3072, nullptr, nullptr, nullptr, nullptr, out_probs, 3,
      M_TOT / 128, 1 << 30, sb2, out_pred);
}

// Round 9
// 764.259 us; speedup vs baseline: 1.3550x; 1.3096x over previous
//
#include <hip/hip_runtime.h>
#include <stdint.h>

#define D_DIM 1024
#define M_TOT 16384        // rows per stream (8*2048)
#define M2 32768           // fused enc+tgt rows
#define N_LAYERS 3
#define NT 16              // K tiles (K=1024 / BK=64)

typedef unsigned short u16;
typedef __attribute__((ext_vector_type(8))) short bf16x8;
typedef __attribute__((ext_vector_type(4))) float f32x4;
typedef __attribute__((ext_vector_type(4))) unsigned short u16x4;

typedef __attribute__((address_space(1))) void gvoid_t;
typedef __attribute__((address_space(3))) void lvoid_t;

__device__ __forceinline__ float b2f(u16 u) {
  union { unsigned int i; float f; } x; x.i = ((unsigned int)u) << 16; return x.f;
}
__device__ __forceinline__ u16 f2b(float f) {  // RNE f32 -> bf16
  union { float f; unsigned int i; } x; x.f = f;
  unsigned int r = x.i + 0x7fffu + ((x.i >> 16) & 1u);
  return (u16)(r >> 16);
}

__device__ __forceinline__ void gload_lds16(const void* g, void* l) {
  __builtin_amdgcn_global_load_lds((gvoid_t*)(uintptr_t)g,
                                   (lvoid_t*)(unsigned int)(uintptr_t)l, 16, 0, 0);
}

// ---------------------------------------------------------------------------
// m97-exact GEMM engine: 128x128 tile, BK=64, 256 thr (2x2 waves, wave tile
// 64x64, 4x4 frags of 16x16x32), SINGLE 32KB LDS buffer, plain 2-barrier
// K-loop (stage -> sync -> compute -> sync), plain C++ LDS reads.
// Mechanism: ~4 blocks/CU co-resident (32KB LDS, <=128 VGPR) give cross-block
// DS||MFMA||HBM overlap (m114/m97) -- no intra-block scheduling needed.
// LDS rows 128B, chunk ^= (row&7) pre-swizzle on the GLOBAL source; reads XOR
// the same -> measured-zero-conflict pattern (R2-R6 evidence, lm=l&15 rows).
// B row-major [N x K] (B^T GEMM). Fused stacks: bmTile<split -> set a, else b.
// EPI 0: outB = bf16(sigmoid(acc+bias) * xfB * decay)
// EPI 1: outB = bf16(acc + bias + xfB)           (pre-LN)
// EPI 2: outB = bf16(p*(acc+bias))               (MoE e0)
// EPI 3: outB = bf16(outB + p*(acc+bias))        (MoE e1,e2)
// EPI 4: outF = outB + p*(acc+bias)              (MoE e3, final f32)
// ---------------------------------------------------------------------------
template <int EPI>
__global__ __launch_bounds__(256, 4) void gemm97(
    const u16* __restrict__ A,
    const u16* __restrict__ B_a, const u16* __restrict__ B_b,
    const float* __restrict__ bias_a, const float* __restrict__ bias_b,
    const float* __restrict__ dec_a, const float* __restrict__ dec_b,
    const u16* __restrict__ xfB, const float* __restrict__ probs, int eIdx,
    int mTiles, int split,
    u16* __restrict__ outB, float* __restrict__ outF)
{
  __shared__ __align__(128) u16 lds[16384];   // 32KB: A[128][64] @0, B @16KB
  const char* ldsc = (const char*)lds;
  int t = threadIdx.x;
  int wid = t >> 6, l = t & 63;
  int wm = wid >> 1, wn = wid & 1;            // 2x2 waves; wave tile 64x64
  int lm = l & 15, g = l >> 4;

  int nwg = mTiles * 8;
  int orig = blockIdx.x;
  int wg = (orig & 7) * (nwg >> 3) + (orig >> 3);   // bijective (nwg % 8 == 0)
  int bmT = wg >> 3, bnT = wg & 7;
  int bm0 = bmT << 7, bn0 = bnT << 7;

  const u16*  Bm   = (bmT < split) ? B_a   : B_b;
  const float* bias = (bmT < split) ? bias_a : bias_b;
  const float* dec  = (bmT < split) ? dec_a  : dec_b;

  // staging: 8 threads per 128B row (16B each), 32 rows/round, 4 rounds/matrix.
  // physical chunk q holds logical chunk q ^ (row&7)  (pre-swizzled source).
  int rowS = t >> 3;                          // 0..31
  int colE = ((t & 7) ^ (rowS & 7)) << 3;     // element col within 64-elem row
  const u16* pA = A  + (size_t)(bm0 + rowS) * D_DIM + colE;
  const u16* pB = Bm + (size_t)(bn0 + rowS) * D_DIM + colE;
  u16* dW = lds + wid * 512;                  // wave-uniform dst (lane*16B implicit)

  f32x4 acc[4][4];
#pragma unroll
  for (int mi = 0; mi < 4; mi++)
#pragma unroll
    for (int ni = 0; ni < 4; ni++) acc[mi][ni] = 0.0f;

  // read-side swizzled k-col byte offsets: logical chunk = ks*4+g, ^ (lm&7)
  unsigned kc0 = (unsigned)(((0 * 4 + g) ^ (lm & 7)) << 4);
  unsigned kc1 = (unsigned)(((1 * 4 + g) ^ (lm & 7)) << 4);
  unsigned rbA = (unsigned)((wm * 64 + lm) * 128);
  unsigned rbB = (unsigned)(16384 + (wn * 64 + lm) * 128);

  for (int kt = 0; kt < NT; ++kt) {
    // ---- stage tile kt (single buffer) ----
    {
      const u16* a0 = pA + kt * 64;
      const u16* b0 = pB + kt * 64;
#pragma unroll
      for (int r = 0; r < 4; r++) {
        gload_lds16(a0 + (size_t)r * 32 * D_DIM, dW + r * 2048);
        gload_lds16(b0 + (size_t)r * 32 * D_DIM, dW + 8192 + r * 2048);
      }
    }
    __syncthreads();    // compiler: s_waitcnt vmcnt(0) lgkmcnt(0) + s_barrier
    // ---- compute tile kt ----
#pragma unroll
    for (int ks = 0; ks < 2; ks++) {
      unsigned kc = ks ? kc1 : kc0;
      bf16x8 av[4], bv[4];
#pragma unroll
      for (int mi = 0; mi < 4; mi++)
        av[mi] = *(const bf16x8*)(ldsc + rbA + mi * 2048 + kc);
#pragma unroll
      for (int ni = 0; ni < 4; ni++)
        bv[ni] = *(const bf16x8*)(ldsc + rbB + ni * 2048 + kc);
#pragma unroll
      for (int mi = 0; mi < 4; mi++)
#pragma unroll
        for (int ni = 0; ni < 4; ni++)
          acc[mi][ni] = __builtin_amdgcn_mfma_f32_16x16x32_bf16(av[mi], bv[ni], acc[mi][ni], 0, 0, 0);
    }
    __syncthreads();    // reads done before next stage overwrites
  }

  // ---- epilogue ----  m = bm0+wm*64+mi*16+g*4+j, n = bn0+wn*64+ni*16+lm
  int nidx[4]; float bia[4], dcv[4];
#pragma unroll
  for (int ni = 0; ni < 4; ni++) {
    nidx[ni] = bn0 + wn * 64 + ni * 16 + lm;
    bia[ni] = bias[nidx[ni]];
    dcv[ni] = (EPI == 0) ? dec[nidx[ni]] : 0.0f;
  }
#pragma unroll
  for (int mi = 0; mi < 4; mi++)
#pragma unroll
    for (int j = 0; j < 4; j++) {
      size_t m = (size_t)bm0 + wm * 64 + mi * 16 + g * 4 + j;
      if (EPI == 0) {
        const u16* xr = xfB + m * D_DIM;
        u16* orow = outB + m * D_DIM;
#pragma unroll
        for (int ni = 0; ni < 4; ni++) {
          float v = acc[mi][ni][j] + bia[ni];
          float gt = 1.0f / (1.0f + __expf(-v));
          orow[nidx[ni]] = f2b(gt * b2f(xr[nidx[ni]]) * dcv[ni]);
        }
      } else if (EPI == 1) {
        const u16* xr = xfB + m * D_DIM;
        u16* orow = outB + m * D_DIM;
#pragma unroll
        for (int ni = 0; ni < 4; ni++)
          orow[nidx[ni]] = f2b(acc[mi][ni][j] + bia[ni] + b2f(xr[nidx[ni]]));
      } else if (EPI == 2) {
        float p = probs[m * 4 + eIdx];
        u16* orow = outB + m * D_DIM;
#pragma unroll
        for (int ni = 0; ni < 4; ni++)
          orow[nidx[ni]] = f2b(p * (acc[mi][ni][j] + bia[ni]));
      } else if (EPI == 3) {
        float p = probs[m * 4 + eIdx];
        u16* orow = outB + m * D_DIM;
#pragma unroll
        for (int ni = 0; ni < 4; ni++)
          orow[nidx[ni]] = f2b(b2f(orow[nidx[ni]]) + p * (acc[mi][ni][j] + bia[ni]));
      } else {
        float p = probs[m * 4 + eIdx];
        const u16* srow = outB + m * D_DIM;
        float* orow = outF + m * D_DIM;
#pragma unroll
        for (int ni = 0; ni < 4; ni++)
          orow[nidx[ni]] = b2f(srow[nidx[ni]]) + p * (acc[mi][ni][j] + bia[ni]);
      }
    }
}

// Fused-stack LayerNorm over D=1024 (rows<M_TOT -> tgt params, else enc).
__global__ __launch_bounds__(256) void ln_fused(const u16* __restrict__ src,
                                                const float* __restrict__ gamT,
                                                const float* __restrict__ betT,
                                                const float* __restrict__ gamE,
                                                const float* __restrict__ betE,
                                                float* __restrict__ dstF,
                                                u16* __restrict__ dstB) {
  size_t row = blockIdx.x;
  const float* gamma = (row < M_TOT) ? gamT : gamE;
  const float* beta  = (row < M_TOT) ? betT : betE;
  int t = threadIdx.x, w = t >> 6, l = t & 63;
  u16x4 vb = ((const u16x4*)(src + row * D_DIM))[t];
  float v[4];
#pragma unroll
  for (int i = 0; i < 4; i++) v[i] = b2f(vb[i]);
  float s = v[0] + v[1] + v[2] + v[3];
  float qs = v[0]*v[0] + v[1]*v[1] + v[2]*v[2] + v[3]*v[3];
#pragma unroll
  for (int off = 32; off; off >>= 1) { s += __shfl_xor(s, off); qs += __shfl_xor(qs, off); }
  __shared__ float red[8];
  if (l == 0) { red[w] = s; red[4 + w] = qs; }
  __syncthreads();
  s = red[0] + red[1] + red[2] + red[3];
  qs = red[4] + red[5] + red[6] + red[7];
  float mu = s * (1.0f / 1024.0f);
  float var = qs * (1.0f / 1024.0f) - mu * mu;
  float inv = rsqrtf(var + 1e-5f);
  f32x4 gm = ((const f32x4*)gamma)[t], b = ((const f32x4*)beta)[t];
  f32x4 y; u16x4 yb;
#pragma unroll
  for (int i = 0; i < 4; i++) { y[i] = (v[i] - mu) * inv * gm[i] + b[i]; yb[i] = f2b(y[i]); }
  ((u16x4*)(dstB + row * D_DIM))[t] = yb;
  if (dstF != nullptr && row < M_TOT) ((f32x4*)(dstF + row * D_DIM))[t] = y;
}

// f32 -> bf16 elementwise
__global__ void conv_kernel(const float* __restrict__ src, u16* __restrict__ dst, int n4) {
  int i = blockIdx.x * 256 + threadIdx.x;
  if (i >= n4) return;
  f32x4 v = ((const f32x4*)src)[i];
  u16x4 o;
#pragma unroll
  for (int j = 0; j < 4; j++) o[j] = f2b(v[j]);
  ((u16x4*)dst)[i] = o;
}

// Gate: logits + softmax -> probs[m,0..3]. One wave per row.
__global__ __launch_bounds__(256) void gate_kernel(const u16* __restrict__ zb,
                                                   const float* __restrict__ gW,
                                                   const float* __restrict__ gb,
                                                   float* __restrict__ probs) {
  __shared__ float sW[4096];
  int t = threadIdx.x;
#pragma unroll
  for (int c = 0; c < 4; c++) ((f32x4*)sW)[c * 256 + t] = ((const f32x4*)gW)[c * 256 + t];
  __syncthreads();
  int w = t >> 6, l = t & 63;
  size_t m = (size_t)blockIdx.x * 4 + w;
  const u16* zr = zb + m * D_DIM;
  float d0 = 0, d1 = 0, d2 = 0, d3 = 0;
#pragma unroll
  for (int c = 0; c < 4; c++) {
    int k = l * 4 + c * 256;
    u16x4 zv = *(const u16x4*)(zr + k);
    f32x4 w0 = *(const f32x4*)&sW[k];
    f32x4 w1 = *(const f32x4*)&sW[1024 + k];
    f32x4 w2 = *(const f32x4*)&sW[2048 + k];
    f32x4 w3 = *(const f32x4*)&sW[3072 + k];
#pragma unroll
    for (int i = 0; i < 4; i++) {
      float zf = b2f(zv[i]);
      d0 += zf * w0[i]; d1 += zf * w1[i]; d2 += zf * w2[i]; d3 += zf * w3[i];
    }
  }
#pragma unroll
  for (int off = 32; off; off >>= 1) {
    d0 += __shfl_xor(d0, off); d1 += __shfl_xor(d1, off);
    d2 += __shfl_xor(d2, off); d3 += __shfl_xor(d3, off);
  }
  if (l == 0) {
    float l0 = d0 + gb[0], l1 = d1 + gb[1], l2 = d2 + gb[2], l3 = d3 + gb[3];
    float mx = fmaxf(fmaxf(l0, l1), fmaxf(l2, l3));
    float e0 = __expf(l0 - mx), e1 = __expf(l1 - mx), e2 = __expf(l2 - mx), e3 = __expf(l3 - mx);
    float inv = 1.0f / (e0 + e1 + e2 + e3);
    f32x4 r; r[0] = e0 * inv; r[1] = e1 * inv; r[2] = e2 * inv; r[3] = e3 * inv;
    ((f32x4*)(probs + m * 4))[0] = r;
  }
}

extern "C" void kernel_launch(void* const* d_in, const int* in_sizes, int n_in,
                              void* d_out, int out_size, void* d_ws, size_t ws_size,
                              hipStream_t stream) {
  (void)in_sizes; (void)n_in; (void)out_size; (void)ws_size;
  const float* x_ctx    = (const float*)d_in[0];
  const float* x_tgt    = (const float*)d_in[1];
  const float* enc_Win  = (const float*)d_in[2];
  const float* enc_bin  = (const float*)d_in[3];
  const float* enc_dec  = (const float*)d_in[4];
  const float* enc_Wout = (const float*)d_in[5];
  const float* enc_bout = (const float*)d_in[6];
  const float* enc_gam  = (const float*)d_in[7];
  const float* enc_bet  = (const float*)d_in[8];
  const float* tgt_Win  = (const float*)d_in[9];
  const float* tgt_bin  = (const float*)d_in[10];
  const float* tgt_dec  = (const float*)d_in[11];
  const float* tgt_Wout = (const float*)d_in[12];
  const float* tgt_bout = (const float*)d_in[13];
  const float* tgt_gam  = (const float*)d_in[14];
  const float* tgt_bet  = (const float*)d_in[15];
  const float* gate_W   = (const float*)d_in[16];
  const float* gate_b   = (const float*)d_in[17];
  const float* exp_W    = (const float*)d_in[18];
  const float* exp_b    = (const float*)d_in[19];

  // d_out: pred_z[16M f32] | gate_probs[64K] | z_target[16M f32]
  float* out_pred  = (float*)d_out;
  float* out_probs = out_pred + (size_t)M_TOT * D_DIM;
  float* out_ztgt  = out_probs + (size_t)M_TOT * 4;

  // ws: bf16 weights (32MB) | xb2 (64MB) | sb2 (64MB) = 160MB.
  // ob2 (pre-LN bf16, 64MB) lives in the out_pred slot (free until final MoE pass).
  char* ws = (char*)d_ws;
  u16* wbTgtIn  = (u16*)ws;
  u16* wbTgtOut = wbTgtIn  + (size_t)3 * 1048576;
  u16* wbEncIn  = wbTgtOut + (size_t)3 * 1048576;
  u16* wbEncOut = wbEncIn  + (size_t)3 * 1048576;
  u16* wbExp    = wbEncOut + (size_t)3 * 1048576;
  u16* xb2      = wbExp    + (size_t)4 * 1048576;
  u16* sb2      = xb2 + (size_t)M2 * D_DIM;
  u16* ob2      = (u16*)out_pred;
  u16* xbCtx    = xb2 + (size_t)M_TOT * D_DIM;

  auto conv = [&](const float* s, u16* d, size_t n) {
    int n4 = (int)(n / 4);
    conv_kernel<<<(n4 + 255) / 256, 256, 0, stream>>>(s, d, n4);
  };
  conv(tgt_Win,  wbTgtIn,  (size_t)3 * 1048576);
  conv(tgt_Wout, wbTgtOut, (size_t)3 * 1048576);
  conv(enc_Win,  wbEncIn,  (size_t)3 * 1048576);
  conv(enc_Wout, wbEncOut, (size_t)3 * 1048576);
  conv(exp_W,    wbExp,    (size_t)4 * 1048576);
  conv(x_tgt, xb2,   (size_t)M_TOT * D_DIM);
  conv(x_ctx, xbCtx, (size_t)M_TOT * D_DIM);

  // ---- fused liquid stacks (rows 0..16383 = tgt, 16384..32767 = enc/ctx) ----
  int nwg2 = M2 / 128 * 8;   // 2048
  for (int i = 0; i < N_LAYERS; i++) {
    size_t wo = (size_t)i * 1048576;
    gemm97<0><<<nwg2, 256, 0, stream>>>(
        xb2, wbTgtIn + wo, wbEncIn + wo,
        tgt_bin + i * 1024, enc_bin + i * 1024,
        tgt_dec + i * 1024, enc_dec + i * 1024,
        xb2, nullptr, 0, M2 / 128, M_TOT / 128, sb2, nullptr);
    gemm97<1><<<nwg2, 256, 0, stream>>>(
        sb2, wbTgtOut + wo, wbEncOut + wo,
        tgt_bout + i * 1024, enc_bout + i * 1024,
        nullptr, nullptr,
        xb2, nullptr, 0, M2 / 128, M_TOT / 128, ob2, nullptr);
    ln_fused<<<M2, 256, 0, stream>>>(ob2,
        tgt_gam + i * 1024, tgt_bet + i * 1024,
        enc_gam + i * 1024, enc_bet + i * 1024,
        (i == N_LAYERS - 1) ? out_ztgt : nullptr, xb2);
  }

  // ---- MoE head on ctx half: gate, then 4 passes (bf16 running sum in sb2) ----
  gate_kernel<<<M_TOT / 4, 256, 0, stream>>>(xbCtx, gate_W, gate_b, out_probs);
  int moeWgs = M_TOT / 128 * 8;   // 1024
  gemm97<2><<<moeWgs, 256, 0, stream>>>(xbCtx, wbExp,               nullptr,
      exp_b,        nullptr, nullptr, nullptr, nullptr, out_probs, 0,
      M_TOT / 128, 1 << 30, sb2, nullptr);
  gemm97<3><<<moeWgs, 256, 0, stream>>>(xbCtx, wbExp + 1048576,     nullptr,
      exp_b + 1024, nullptr, nullptr, nullptr, nullptr, out_probs, 1,
      M_TOT / 128, 1 << 30, sb2, nullptr);
  gemm97<3><<<moeWgs, 256, 0, stream>>>(xbCtx, wbExp + 2 * 1048576, nullptr,
      exp_b + 2048, nullptr, nullptr, nullptr, nullptr, out_probs, 2,
      M_TOT / 128, 1 << 30, sb2, nullptr);
  gemm97<4><<<moeWgs, 256, 0, stream>>>(xbCtx, wbExp + 3 * 1048576, nullptr,
      exp_b + 3072, nullptr, nullptr, nullptr, nullptr, out_probs, 3,
      M_TOT / 128, 1 << 30, sb2, out_pred);
}